// Round 1
// baseline (2334.936 us; speedup 1.0000x reference)
//
#include <hip/hip_runtime.h>

// MoE top-1 (ColossalAI-style) on MI355X — round 0: fp32 correctness baseline.
// T=8192 tokens, D=1024, E=8, DFF=4096, CAP=1280.
// ws layout (bytes):
//   [0,32)            me_sum  f32[8]
//   [32,32800)        top1    i32[8192]
//   [32800,65568)     p1      f32[8192]
//   [65568,98336)     rankk   i32[8192]   (rank if kept else -1)
//   [98336,139296)    slot_token i32[10240]
//   [139296,+41943040)   X    f32[E*CAP*D]
//   [42082336,+83886080) H    bf16[E*CAP*DFF]
// total ~126 MB.

#define TKN    8192
#define DMODEL 1024
#define NEXP   8
#define DFFN   4096
#define CAPC   1280

__device__ __forceinline__ unsigned short f2bf(float f) {
  unsigned int u = __float_as_uint(f);
  u += 0x7fffu + ((u >> 16) & 1u);          // RNE
  return (unsigned short)(u >> 16);
}
__device__ __forceinline__ float bf2f(unsigned short h) {
  return __uint_as_float(((unsigned int)h) << 16);
}
__device__ __forceinline__ float gelu_tanh(float x) {
  const float c0 = 0.7978845608028654f;
  const float c1 = 0.044715f;
  float inner = c0 * (x + c1 * x * x * x);
  return 0.5f * x * (1.0f + tanhf(inner));
}

// ---------------- init: zero me_sum, slot_token = -1 ----------------
__global__ __launch_bounds__(256) void k_init(int* __restrict__ slot_token,
                                              float* __restrict__ me_sum) {
  int i = blockIdx.x * 256 + threadIdx.x;
  if (i < NEXP * CAPC) slot_token[i] = -1;
  if (i < NEXP) me_sum[i] = 0.0f;
}

// ---------------- gating: one wave per token ----------------
__global__ __launch_bounds__(256) void k_gate(const float* __restrict__ x,
                                              const float* __restrict__ gw,
                                              int* __restrict__ top1,
                                              float* __restrict__ p1,
                                              float* __restrict__ me_sum) {
  const int wave = threadIdx.x >> 6;
  const int lane = threadIdx.x & 63;
  const int t = blockIdx.x * 4 + wave;
  const float* xrow = x + (size_t)t * DMODEL;

  float acc[NEXP] = {};
  for (int k = lane; k < DMODEL; k += 64) {
    float xv = xrow[k];
#pragma unroll
    for (int e = 0; e < NEXP; ++e) acc[e] = fmaf(xv, gw[e * DMODEL + k], acc[e]);
  }
#pragma unroll
  for (int e = 0; e < NEXP; ++e) {
    float v = acc[e];
    v += __shfl_xor(v, 32);
    v += __shfl_xor(v, 16);
    v += __shfl_xor(v, 8);
    v += __shfl_xor(v, 4);
    v += __shfl_xor(v, 2);
    v += __shfl_xor(v, 1);
    acc[e] = v;
  }
  // all lanes now hold identical logits
  float m = acc[0];
  int idx = 0;
#pragma unroll
  for (int e = 1; e < NEXP; ++e) {
    if (acc[e] > m) { m = acc[e]; idx = e; }   // first-max wins on ties
  }
  float pe[NEXP];
  float s = 0.0f;
#pragma unroll
  for (int e = 0; e < NEXP; ++e) { pe[e] = expf(acc[e] - m); s += pe[e]; }
  float inv = 1.0f / s;

  __shared__ float lme[4][NEXP];
  if (lane == 0) {
#pragma unroll
    for (int e = 0; e < NEXP; ++e) lme[wave][e] = pe[e] * inv;
    top1[t] = idx;
    p1[t] = inv;  // pe[idx] == exp(0) == 1 exactly
  }
  __syncthreads();
  if (threadIdx.x < NEXP) {
    float v = lme[0][threadIdx.x] + lme[1][threadIdx.x] + lme[2][threadIdx.x] + lme[3][threadIdx.x];
    atomicAdd(&me_sum[threadIdx.x], v);
  }
}

// ---------------- ordered rank scan (single block) ----------------
__global__ __launch_bounds__(1024) void k_scan(const int* __restrict__ top1,
                                               const float* __restrict__ me_sum,
                                               int* __restrict__ rankk,
                                               float* __restrict__ out_laux) {
  __shared__ int base[NEXP];
  __shared__ int wcnt[16][NEXP];
  const int tid = threadIdx.x;
  const int w = tid >> 6, lane = tid & 63;
  if (tid < NEXP) base[tid] = 0;
  __syncthreads();

  for (int r = 0; r < TKN; r += 1024) {
    int e = top1[r + tid];
    int myrank = 0;
#pragma unroll
    for (int ee = 0; ee < NEXP; ++ee) {
      unsigned long long b = __ballot(e == ee);
      if (ee == e) myrank = __popcll(b & ((1ull << lane) - 1ull));
      if (lane == 0) wcnt[w][ee] = __popcll(b);
    }
    __syncthreads();
    int pre = base[e];
    for (int ww = 0; ww < w; ++ww) pre += wcnt[ww][e];
    int rank = pre + myrank;
    rankk[r + tid] = (rank < CAPC) ? rank : -1;
    __syncthreads();
    if (tid < NEXP) {
      int s = 0;
#pragma unroll
      for (int ww = 0; ww < 16; ++ww) s += wcnt[ww][tid];
      base[tid] += s;  // pre-capacity running count (ce uses this)
    }
    __syncthreads();
  }

  if (tid == 0) {
    float s = 0.0f;
    for (int e = 0; e < NEXP; ++e) {
      float me = me_sum[e] * (1.0f / (float)TKN);
      float ce = (float)base[e] * (1.0f / (float)TKN);
      s += me * ce;
    }
    *out_laux = (float)NEXP * s;
  }
}

// ---------------- dispatch scatter / zero dropped rows ----------------
__global__ __launch_bounds__(256) void k_dispatch(const float* __restrict__ x,
                                                  const int* __restrict__ top1,
                                                  const int* __restrict__ rankk,
                                                  int* __restrict__ slot_token,
                                                  float* __restrict__ X,
                                                  float* __restrict__ out) {
  const int t = blockIdx.x;
  const int tid = threadIdx.x;
  const int r = rankk[t];
  if (r < 0) {
    float4 z = {0.f, 0.f, 0.f, 0.f};
    *(float4*)(out + (size_t)t * DMODEL + tid * 4) = z;
    return;
  }
  const int e = top1[t];
  const int slot = e * CAPC + r;
  if (tid == 0) slot_token[slot] = t;
  float4 v = *(const float4*)(x + (size_t)t * DMODEL + tid * 4);
  *(float4*)(X + (size_t)slot * DMODEL + tid * 4) = v;
}

// ---------------- FFN1: H = gelu(X @ w1 + b1), bf16 out ----------------
__global__ __launch_bounds__(256) void k_ffn1(const float* __restrict__ X,
                                              const float* __restrict__ w1,
                                              const float* __restrict__ b1,
                                              unsigned short* __restrict__ H) {
  const int e = blockIdx.z, mt = blockIdx.y, nt = blockIdx.x;
  __shared__ float As[16][68];
  __shared__ float Bs[16][68];
  const int tid = threadIdx.x;
  const int tx = tid & 15, ty = tid >> 4;
  const int lm = tid >> 2, lk4 = (tid & 3) << 2;
  const int wk = tid >> 4, wn4 = (tid & 15) << 2;

  const float* Arow = X + ((size_t)(e * CAPC + mt * 64 + lm)) * DMODEL + lk4;
  const float* Wcol = w1 + (size_t)e * DMODEL * DFFN + (size_t)wk * DFFN + nt * 64 + wn4;

  float acc[4][4] = {};
  for (int k0 = 0; k0 < DMODEL; k0 += 16) {
    float4 av = *(const float4*)(Arow + k0);
    As[lk4 + 0][lm] = av.x;
    As[lk4 + 1][lm] = av.y;
    As[lk4 + 2][lm] = av.z;
    As[lk4 + 3][lm] = av.w;
    *(float4*)&Bs[wk][wn4] = *(const float4*)(Wcol + (size_t)k0 * DFFN);
    __syncthreads();
#pragma unroll
    for (int k = 0; k < 16; ++k) {
      float4 a = *(const float4*)&As[k][ty << 2];
      float4 b = *(const float4*)&Bs[k][tx << 2];
      float ar[4] = {a.x, a.y, a.z, a.w};
      float br[4] = {b.x, b.y, b.z, b.w};
#pragma unroll
      for (int i = 0; i < 4; ++i)
#pragma unroll
        for (int j = 0; j < 4; ++j) acc[i][j] = fmaf(ar[i], br[j], acc[i][j]);
    }
    __syncthreads();
  }

  const int f0 = nt * 64 + (tx << 2);
  float4 bb = *(const float4*)(b1 + e * DFFN + f0);
  float bbr[4] = {bb.x, bb.y, bb.z, bb.w};
#pragma unroll
  for (int i = 0; i < 4; ++i) {
    const int c = mt * 64 + (ty << 2) + i;
    size_t off = ((size_t)(e * CAPC + c)) * DFFN + f0;
    ushort4 hv;
    hv.x = f2bf(gelu_tanh(acc[i][0] + bbr[0]));
    hv.y = f2bf(gelu_tanh(acc[i][1] + bbr[1]));
    hv.z = f2bf(gelu_tanh(acc[i][2] + bbr[2]));
    hv.w = f2bf(gelu_tanh(acc[i][3] + bbr[3]));
    *(ushort4*)(H + off) = hv;
  }
}

// ---------------- FFN2 + fused combine ----------------
__global__ __launch_bounds__(256) void k_ffn2(const unsigned short* __restrict__ H,
                                              const float* __restrict__ w2,
                                              const float* __restrict__ b2,
                                              const int* __restrict__ slot_token,
                                              const float* __restrict__ p1,
                                              float* __restrict__ out) {
  const int e = blockIdx.z, mt = blockIdx.y, nt = blockIdx.x;
  __shared__ float As[16][68];
  __shared__ float Bs[16][68];
  const int tid = threadIdx.x;
  const int tx = tid & 15, ty = tid >> 4;
  const int lm = tid >> 2, lk4 = (tid & 3) << 2;
  const int wk = tid >> 4, wn4 = (tid & 15) << 2;

  const unsigned short* Arow = H + ((size_t)(e * CAPC + mt * 64 + lm)) * DFFN + lk4;
  const float* Wcol = w2 + (size_t)e * DFFN * DMODEL + (size_t)wk * DMODEL + nt * 64 + wn4;

  float acc[4][4] = {};
  for (int k0 = 0; k0 < DFFN; k0 += 16) {
    ushort4 av = *(const ushort4*)(Arow + k0);
    As[lk4 + 0][lm] = bf2f(av.x);
    As[lk4 + 1][lm] = bf2f(av.y);
    As[lk4 + 2][lm] = bf2f(av.z);
    As[lk4 + 3][lm] = bf2f(av.w);
    *(float4*)&Bs[wk][wn4] = *(const float4*)(Wcol + (size_t)k0 * DMODEL);
    __syncthreads();
#pragma unroll
    for (int k = 0; k < 16; ++k) {
      float4 a = *(const float4*)&As[k][ty << 2];
      float4 b = *(const float4*)&Bs[k][tx << 2];
      float ar[4] = {a.x, a.y, a.z, a.w};
      float br[4] = {b.x, b.y, b.z, b.w};
#pragma unroll
      for (int i = 0; i < 4; ++i)
#pragma unroll
        for (int j = 0; j < 4; ++j) acc[i][j] = fmaf(ar[i], br[j], acc[i][j]);
    }
    __syncthreads();
  }

  const int n0 = nt * 64 + (tx << 2);
  float4 bb = *(const float4*)(b2 + e * DMODEL + n0);
  float bbr[4] = {bb.x, bb.y, bb.z, bb.w};
#pragma unroll
  for (int i = 0; i < 4; ++i) {
    const int c = mt * 64 + (ty << 2) + i;
    const int t = slot_token[e * CAPC + c];
    if (t >= 0) {
      float p = p1[t];
      float4 o;
      o.x = p * (acc[i][0] + bbr[0]);
      o.y = p * (acc[i][1] + bbr[1]);
      o.z = p * (acc[i][2] + bbr[2]);
      o.w = p * (acc[i][3] + bbr[3]);
      *(float4*)(out + (size_t)t * DMODEL + n0) = o;
    }
  }
}

extern "C" void kernel_launch(void* const* d_in, const int* in_sizes, int n_in,
                              void* d_out, int out_size, void* d_ws, size_t ws_size,
                              hipStream_t stream) {
  const float* x  = (const float*)d_in[0];
  const float* gw = (const float*)d_in[1];
  const float* w1 = (const float*)d_in[2];
  const float* b1 = (const float*)d_in[3];
  const float* w2 = (const float*)d_in[4];
  const float* b2 = (const float*)d_in[5];
  float* out = (float*)d_out;

  char* ws = (char*)d_ws;
  float* me_sum       = (float*)(ws + 0);
  int*   top1         = (int*)(ws + 32);
  float* p1           = (float*)(ws + 32800);
  int*   rankk        = (int*)(ws + 65568);
  int*   slot_token   = (int*)(ws + 98336);
  float* X            = (float*)(ws + 139296);
  unsigned short* H   = (unsigned short*)(ws + 42082336);

  k_init<<<40, 256, 0, stream>>>(slot_token, me_sum);
  k_gate<<<TKN / 4, 256, 0, stream>>>(x, gw, top1, p1, me_sum);
  k_scan<<<1, 1024, 0, stream>>>(top1, me_sum, rankk, out + (size_t)TKN * DMODEL);
  k_dispatch<<<TKN, 256, 0, stream>>>(x, top1, rankk, slot_token, X, out);
  dim3 g1(DFFN / 64, CAPC / 64, NEXP);
  k_ffn1<<<g1, 256, 0, stream>>>(X, w1, b1, H);
  dim3 g2(DMODEL / 64, CAPC / 64, NEXP);
  k_ffn2<<<g2, 256, 0, stream>>>(H, w2, b2, slot_token, p1, out);
}

// Round 2
// 787.639 us; speedup vs baseline: 2.9645x; 2.9645x over previous
//
#include <hip/hip_runtime.h>

// MoE top-1 (ColossalAI-style) on MI355X — round 1: bf16 MFMA FFN (m97 structure).
// T=8192, D=1024, E=8, DFF=4096, CAP=1280. DFF split into 2 halves of 2048 to
// bound ws at ~97 MB (Xb 21 + H_half 42 + WB 33.5).

#define TKN    8192
#define DMODEL 1024
#define NEXP   8
#define DFFN   4096
#define CAPC   1280

typedef __attribute__((ext_vector_type(8))) short short8;
typedef __attribute__((ext_vector_type(4))) float f32x4;

__device__ __forceinline__ unsigned short f2bf(float f) {
  unsigned int u = __float_as_uint(f);
  u += 0x7fffu + ((u >> 16) & 1u);          // RNE
  return (unsigned short)(u >> 16);
}
__device__ __forceinline__ float gelu_tanh(float x) {
  const float c0 = 0.7978845608028654f;
  const float c1 = 0.044715f;
  float inner = c0 * (x + c1 * x * x * x);
  return 0.5f * x * (1.0f + tanhf(inner));
}
__device__ __forceinline__ void gload_lds16(const void* g, void* l) {
  __builtin_amdgcn_global_load_lds(
      (const __attribute__((address_space(1))) void*)g,
      (__attribute__((address_space(3))) void*)l, 16, 0, 0);
}

// ---------------- init ----------------
__global__ __launch_bounds__(256) void k_init(int* __restrict__ slot_token,
                                              float* __restrict__ me_sum) {
  int i = blockIdx.x * 256 + threadIdx.x;
  if (i < NEXP * CAPC) slot_token[i] = -1;
  if (i < NEXP) me_sum[i] = 0.0f;
}

// ---------------- gating: one wave per token (fp32, bit-exact argmax) ----------------
__global__ __launch_bounds__(256) void k_gate(const float* __restrict__ x,
                                              const float* __restrict__ gw,
                                              int* __restrict__ top1,
                                              float* __restrict__ p1,
                                              float* __restrict__ me_sum) {
  const int wave = threadIdx.x >> 6;
  const int lane = threadIdx.x & 63;
  const int t = blockIdx.x * 4 + wave;
  const float* xrow = x + (size_t)t * DMODEL;

  float acc[NEXP] = {};
  for (int k = lane; k < DMODEL; k += 64) {
    float xv = xrow[k];
#pragma unroll
    for (int e = 0; e < NEXP; ++e) acc[e] = fmaf(xv, gw[e * DMODEL + k], acc[e]);
  }
#pragma unroll
  for (int e = 0; e < NEXP; ++e) {
    float v = acc[e];
    v += __shfl_xor(v, 32); v += __shfl_xor(v, 16); v += __shfl_xor(v, 8);
    v += __shfl_xor(v, 4);  v += __shfl_xor(v, 2);  v += __shfl_xor(v, 1);
    acc[e] = v;
  }
  float m = acc[0];
  int idx = 0;
#pragma unroll
  for (int e = 1; e < NEXP; ++e) {
    if (acc[e] > m) { m = acc[e]; idx = e; }
  }
  float pe[NEXP];
  float s = 0.0f;
#pragma unroll
  for (int e = 0; e < NEXP; ++e) { pe[e] = expf(acc[e] - m); s += pe[e]; }
  float inv = 1.0f / s;

  __shared__ float lme[4][NEXP];
  if (lane == 0) {
#pragma unroll
    for (int e = 0; e < NEXP; ++e) lme[wave][e] = pe[e] * inv;
    top1[t] = idx;
    p1[t] = inv;  // exp(top1 - max) == 1 exactly
  }
  __syncthreads();
  if (threadIdx.x < NEXP) {
    float v = lme[0][threadIdx.x] + lme[1][threadIdx.x] + lme[2][threadIdx.x] + lme[3][threadIdx.x];
    atomicAdd(&me_sum[threadIdx.x], v);
  }
}

// ---------------- ordered rank scan (single block) ----------------
__global__ __launch_bounds__(1024) void k_scan(const int* __restrict__ top1,
                                               const float* __restrict__ me_sum,
                                               int* __restrict__ rankk,
                                               float* __restrict__ out_laux) {
  __shared__ int base[NEXP];
  __shared__ int wcnt[16][NEXP];
  const int tid = threadIdx.x;
  const int w = tid >> 6, lane = tid & 63;
  if (tid < NEXP) base[tid] = 0;
  __syncthreads();

  for (int r = 0; r < TKN; r += 1024) {
    int e = top1[r + tid];
    int myrank = 0;
#pragma unroll
    for (int ee = 0; ee < NEXP; ++ee) {
      unsigned long long b = __ballot(e == ee);
      if (ee == e) myrank = __popcll(b & ((1ull << lane) - 1ull));
      if (lane == 0) wcnt[w][ee] = __popcll(b);
    }
    __syncthreads();
    int pre = base[e];
    for (int ww = 0; ww < w; ++ww) pre += wcnt[ww][e];
    int rank = pre + myrank;
    rankk[r + tid] = (rank < CAPC) ? rank : -1;
    __syncthreads();
    if (tid < NEXP) {
      int s = 0;
#pragma unroll
      for (int ww = 0; ww < 16; ++ww) s += wcnt[ww][tid];
      base[tid] += s;  // pre-capacity count (ce uses this)
    }
    __syncthreads();
  }

  if (tid == 0) {
    float s = 0.0f;
    for (int e = 0; e < NEXP; ++e) {
      float me = me_sum[e] * (1.0f / (float)TKN);
      float ce = (float)base[e] * (1.0f / (float)TKN);
      s += me * ce;
    }
    *out_laux = (float)NEXP * s;
  }
}

// ---------------- dispatch: scatter tokens as bf16, zero dropped out rows ----------------
__global__ __launch_bounds__(256) void k_dispatch(const float* __restrict__ x,
                                                  const int* __restrict__ top1,
                                                  const int* __restrict__ rankk,
                                                  int* __restrict__ slot_token,
                                                  unsigned short* __restrict__ Xb,
                                                  float* __restrict__ out) {
  const int t = blockIdx.x;
  const int tid = threadIdx.x;
  const int r = rankk[t];
  if (r < 0) {
    float4 z = {0.f, 0.f, 0.f, 0.f};
    *(float4*)(out + (size_t)t * DMODEL + tid * 4) = z;
    return;
  }
  const int e = top1[t];
  const int slot = e * CAPC + r;
  if (tid == 0) slot_token[slot] = t;
  float4 v = *(const float4*)(x + (size_t)t * DMODEL + tid * 4);
  ushort4 h;
  h.x = f2bf(v.x); h.y = f2bf(v.y); h.z = f2bf(v.z); h.w = f2bf(v.w);
  *(ushort4*)(Xb + (size_t)slot * DMODEL + tid * 4) = h;
}

// ---------------- weight transpose + fp32->bf16: W[e][K][N] -> WT[e][Nt][Kt] ----------------
__global__ __launch_bounds__(256) void k_wtrans(const float* __restrict__ W,
                                                unsigned short* __restrict__ WT,
                                                int K, int N, int k_off, int Kt,
                                                int n_off, int Nt) {
  __shared__ float ls[32][33];
  const int e = blockIdx.z, kt = blockIdx.y, nt = blockIdx.x;
  const int t = threadIdx.x;
  {
    const int kl = t >> 3, nl0 = (t & 7) * 4;
    const float* src = W + (size_t)e * K * N + (size_t)(k_off + kt * 32 + kl) * N + n_off + nt * 32 + nl0;
    float4 v = *(const float4*)src;
    ls[kl][nl0 + 0] = v.x; ls[kl][nl0 + 1] = v.y;
    ls[kl][nl0 + 2] = v.z; ls[kl][nl0 + 3] = v.w;
  }
  __syncthreads();
  {
    const int nl = t >> 3, kl0 = (t & 7) * 4;
    ushort4 o;
    o.x = f2bf(ls[kl0 + 0][nl]); o.y = f2bf(ls[kl0 + 1][nl]);
    o.z = f2bf(ls[kl0 + 2][nl]); o.w = f2bf(ls[kl0 + 3][nl]);
    *(ushort4*)(WT + (size_t)e * Nt * Kt + (size_t)(nt * 32 + nl) * Kt + kt * 32 + kl0) = o;
  }
}

// ---------------- MFMA GEMM: C[128x128] = A[128xK] * B^T[128xK], m97 structure ----------------
// MODE 0: H = f2bf(gelu(acc + b1))     MODE 1: out[t] = p*acc     MODE 2: out[t] += p*(acc + b2)
template <int MODE>
__global__ __launch_bounds__(256) void k_gemm(
    const unsigned short* __restrict__ A, int lda,
    const unsigned short* __restrict__ Bm, int ldb,
    int nK,
    const float* __restrict__ bias, int bias_off, int bias_ld,
    unsigned short* __restrict__ Hout, int ldh,
    const int* __restrict__ slot_token,
    const float* __restrict__ p1,
    float* __restrict__ out) {
  __shared__ __align__(16) unsigned short As[128 * 64];
  __shared__ __align__(16) unsigned short Bs[128 * 64];
  const int e = blockIdx.z, mt = blockIdx.y, nt = blockIdx.x;
  const int tid = threadIdx.x;
  const int w = tid >> 6, lane = tid & 63;
  const int wr = w >> 1, wc = w & 1;
  const int N = gridDim.x * 128;

  const unsigned short* Abase = A + (size_t)(e * CAPC + mt * 128) * lda;
  const unsigned short* Bbase = Bm + (size_t)e * N * ldb + (size_t)(nt * 128) * ldb;

  const int srow = w * 32 + (lane >> 3);   // + j*8
  const int scol = (lane & 7) * 8;
  unsigned short* ldsA = &As[(w * 32) * 64];
  unsigned short* ldsB = &Bs[(w * 32) * 64];

  f32x4 acc[4][4];
#pragma unroll
  for (int m = 0; m < 4; ++m)
#pragma unroll
    for (int n = 0; n < 4; ++n) acc[m][n] = (f32x4){0.f, 0.f, 0.f, 0.f};

  const int arow = wr * 64 + (lane & 15);  // + m*16
  const int brow = wc * 64 + (lane & 15);  // + n*16
  const int kcol = (lane >> 4) * 8;        // + kk

  for (int t = 0; t < nK; ++t) {
    const size_t k0 = (size_t)t * 64;
#pragma unroll
    for (int j = 0; j < 4; ++j)
      gload_lds16(Abase + (size_t)(srow + j * 8) * lda + k0 + scol, ldsA + j * 8 * 64);
#pragma unroll
    for (int j = 0; j < 4; ++j)
      gload_lds16(Bbase + (size_t)(srow + j * 8) * ldb + k0 + scol, ldsB + j * 8 * 64);
    __syncthreads();
#pragma unroll
    for (int kk = 0; kk < 64; kk += 32) {
      short8 av[4], bv[4];
#pragma unroll
      for (int m = 0; m < 4; ++m) av[m] = *(const short8*)&As[(arow + m * 16) * 64 + kk + kcol];
#pragma unroll
      for (int n = 0; n < 4; ++n) bv[n] = *(const short8*)&Bs[(brow + n * 16) * 64 + kk + kcol];
#pragma unroll
      for (int m = 0; m < 4; ++m)
#pragma unroll
        for (int n = 0; n < 4; ++n)
          acc[m][n] = __builtin_amdgcn_mfma_f32_16x16x32_bf16(av[m], bv[n], acc[m][n], 0, 0, 0);
    }
    __syncthreads();
  }

  const int colf = lane & 15;
  const int rsub = (lane >> 4) * 4;
#pragma unroll
  for (int m = 0; m < 4; ++m) {
#pragma unroll
    for (int i = 0; i < 4; ++i) {
      const int slot_l = mt * 128 + wr * 64 + m * 16 + rsub + i;
      if (MODE == 0) {
        const size_t hrow = ((size_t)(e * CAPC) + slot_l) * ldh;
#pragma unroll
        for (int n = 0; n < 4; ++n) {
          const int col = nt * 128 + wc * 64 + n * 16 + colf;
          float v = acc[m][n][i] + bias[e * bias_ld + bias_off + col];
          Hout[hrow + col] = f2bf(gelu_tanh(v));
        }
      } else {
        const int slotg = e * CAPC + slot_l;
        const int tkn = slot_token[slotg];
        if (tkn >= 0) {
          const float p = p1[tkn];
#pragma unroll
          for (int n = 0; n < 4; ++n) {
            const int col = nt * 128 + wc * 64 + n * 16 + colf;
            float v = acc[m][n][i];
            if (MODE == 2) v += bias[e * bias_ld + col];
            float o = p * v;
            float* dst = out + (size_t)tkn * DMODEL + col;
            if (MODE == 2) *dst = *dst + o;
            else *dst = o;
          }
        }
      }
    }
  }
}

extern "C" void kernel_launch(void* const* d_in, const int* in_sizes, int n_in,
                              void* d_out, int out_size, void* d_ws, size_t ws_size,
                              hipStream_t stream) {
  const float* x  = (const float*)d_in[0];
  const float* gw = (const float*)d_in[1];
  const float* w1 = (const float*)d_in[2];
  const float* b1 = (const float*)d_in[3];
  const float* w2 = (const float*)d_in[4];
  const float* b2 = (const float*)d_in[5];
  float* out = (float*)d_out;

  char* ws = (char*)d_ws;
  float* me_sum     = (float*)(ws + 0);
  int*   top1       = (int*)(ws + 1024);
  float* p1         = (float*)(ws + 33792);
  int*   rankk      = (int*)(ws + 66560);
  int*   slot_token = (int*)(ws + 99328);
  unsigned short* Xb = (unsigned short*)(ws + 140288);               // 10240*1024*2  = 20.97 MB
  unsigned short* H  = (unsigned short*)(ws + 21111808);             // 10240*2048*2  = 41.94 MB
  unsigned short* WB = (unsigned short*)(ws + 63054848);             // 33.55 MB
  // total ~96.6 MB

  k_init<<<40, 256, 0, stream>>>(slot_token, me_sum);
  k_gate<<<TKN / 4, 256, 0, stream>>>(x, gw, top1, p1, me_sum);
  k_scan<<<1, 1024, 0, stream>>>(top1, me_sum, rankk, out + (size_t)TKN * DMODEL);
  k_dispatch<<<TKN, 256, 0, stream>>>(x, top1, rankk, slot_token, Xb, out);

  // ---- half 0 (f in [0,2048)) ----
  k_wtrans<<<dim3(64, 32, NEXP), 256, 0, stream>>>(w1, WB, DMODEL, DFFN, 0, DMODEL, 0, 2048);
  k_gemm<0><<<dim3(16, 10, NEXP), 256, 0, stream>>>(Xb, DMODEL, WB, DMODEL, DMODEL / 64,
                                                    b1, 0, DFFN, H, 2048,
                                                    nullptr, nullptr, nullptr);
  k_wtrans<<<dim3(32, 64, NEXP), 256, 0, stream>>>(w2, WB, DFFN, DMODEL, 0, 2048, 0, DMODEL);
  k_gemm<1><<<dim3(8, 10, NEXP), 256, 0, stream>>>(H, 2048, WB, 2048, 2048 / 64,
                                                   b2, 0, DMODEL, nullptr, 0,
                                                   slot_token, p1, out);

  // ---- half 1 (f in [2048,4096)) ----
  k_wtrans<<<dim3(64, 32, NEXP), 256, 0, stream>>>(w1, WB, DMODEL, DFFN, 0, DMODEL, 2048, 2048);
  k_gemm<0><<<dim3(16, 10, NEXP), 256, 0, stream>>>(Xb, DMODEL, WB, DMODEL, DMODEL / 64,
                                                    b1, 2048, DFFN, H, 2048,
                                                    nullptr, nullptr, nullptr);
  k_wtrans<<<dim3(32, 64, NEXP), 256, 0, stream>>>(w2, WB, DFFN, DMODEL, 2048, 2048, 0, DMODEL);
  k_gemm<2><<<dim3(8, 10, NEXP), 256, 0, stream>>>(H, 2048, WB, 2048, 2048 / 64,
                                                   b2, 0, DMODEL, nullptr, 0,
                                                   slot_token, p1, out);
}

// Round 3
// 722.320 us; speedup vs baseline: 3.2325x; 1.0904x over previous
//
#include <hip/hip_runtime.h>

// MoE top-1 (ColossalAI-style) on MI355X — round 2: dbuf + counted-vmcnt pipeline
// + LDS XOR swizzle in the MFMA GEMMs. T=8192, D=1024, E=8, DFF=4096, CAP=1280.

#define TKN    8192
#define DMODEL 1024
#define NEXP   8
#define DFFN   4096
#define CAPC   1280

typedef __attribute__((ext_vector_type(8))) short short8;
typedef __attribute__((ext_vector_type(4))) float f32x4;

__device__ __forceinline__ unsigned short f2bf(float f) {
  unsigned int u = __float_as_uint(f);
  u += 0x7fffu + ((u >> 16) & 1u);          // RNE
  return (unsigned short)(u >> 16);
}
__device__ __forceinline__ float gelu_tanh(float x) {
  const float c0 = 0.7978845608028654f;
  const float c1 = 0.044715f;
  float inner = c0 * (x + c1 * x * x * x);
  return 0.5f * x * (1.0f + tanhf(inner));
}
__device__ __forceinline__ void gload_lds16(const void* g, void* l) {
  __builtin_amdgcn_global_load_lds(
      (const __attribute__((address_space(1))) void*)g,
      (__attribute__((address_space(3))) void*)l, 16, 0, 0);
}

// ---------------- init ----------------
__global__ __launch_bounds__(256) void k_init(int* __restrict__ slot_token,
                                              float* __restrict__ me_sum) {
  int i = blockIdx.x * 256 + threadIdx.x;
  if (i < NEXP * CAPC) slot_token[i] = -1;
  if (i < NEXP) me_sum[i] = 0.0f;
}

// ---------------- gating: one wave per token (fp32, bit-exact argmax) ----------------
__global__ __launch_bounds__(256) void k_gate(const float* __restrict__ x,
                                              const float* __restrict__ gw,
                                              int* __restrict__ top1,
                                              float* __restrict__ p1,
                                              float* __restrict__ me_sum) {
  const int wave = threadIdx.x >> 6;
  const int lane = threadIdx.x & 63;
  const int t = blockIdx.x * 4 + wave;
  const float* xrow = x + (size_t)t * DMODEL;

  float acc[NEXP] = {};
  for (int k = lane; k < DMODEL; k += 64) {
    float xv = xrow[k];
#pragma unroll
    for (int e = 0; e < NEXP; ++e) acc[e] = fmaf(xv, gw[e * DMODEL + k], acc[e]);
  }
#pragma unroll
  for (int e = 0; e < NEXP; ++e) {
    float v = acc[e];
    v += __shfl_xor(v, 32); v += __shfl_xor(v, 16); v += __shfl_xor(v, 8);
    v += __shfl_xor(v, 4);  v += __shfl_xor(v, 2);  v += __shfl_xor(v, 1);
    acc[e] = v;
  }
  float m = acc[0];
  int idx = 0;
#pragma unroll
  for (int e = 1; e < NEXP; ++e) {
    if (acc[e] > m) { m = acc[e]; idx = e; }
  }
  float pe[NEXP];
  float s = 0.0f;
#pragma unroll
  for (int e = 0; e < NEXP; ++e) { pe[e] = expf(acc[e] - m); s += pe[e]; }
  float inv = 1.0f / s;

  __shared__ float lme[4][NEXP];
  if (lane == 0) {
#pragma unroll
    for (int e = 0; e < NEXP; ++e) lme[wave][e] = pe[e] * inv;
    top1[t] = idx;
    p1[t] = inv;  // exp(top1 - max) == 1 exactly
  }
  __syncthreads();
  if (threadIdx.x < NEXP) {
    float v = lme[0][threadIdx.x] + lme[1][threadIdx.x] + lme[2][threadIdx.x] + lme[3][threadIdx.x];
    atomicAdd(&me_sum[threadIdx.x], v);
  }
}

// ---------------- ordered rank scan (single block) ----------------
__global__ __launch_bounds__(1024) void k_scan(const int* __restrict__ top1,
                                               const float* __restrict__ me_sum,
                                               int* __restrict__ rankk,
                                               float* __restrict__ out_laux) {
  __shared__ int base[NEXP];
  __shared__ int wcnt[16][NEXP];
  const int tid = threadIdx.x;
  const int w = tid >> 6, lane = tid & 63;
  if (tid < NEXP) base[tid] = 0;
  __syncthreads();

  for (int r = 0; r < TKN; r += 1024) {
    int e = top1[r + tid];
    int myrank = 0;
#pragma unroll
    for (int ee = 0; ee < NEXP; ++ee) {
      unsigned long long b = __ballot(e == ee);
      if (ee == e) myrank = __popcll(b & ((1ull << lane) - 1ull));
      if (lane == 0) wcnt[w][ee] = __popcll(b);
    }
    __syncthreads();
    int pre = base[e];
    for (int ww = 0; ww < w; ++ww) pre += wcnt[ww][e];
    int rank = pre + myrank;
    rankk[r + tid] = (rank < CAPC) ? rank : -1;
    __syncthreads();
    if (tid < NEXP) {
      int s = 0;
#pragma unroll
      for (int ww = 0; ww < 16; ++ww) s += wcnt[ww][tid];
      base[tid] += s;  // pre-capacity count (ce uses this)
    }
    __syncthreads();
  }

  if (tid == 0) {
    float s = 0.0f;
    for (int e = 0; e < NEXP; ++e) {
      float me = me_sum[e] * (1.0f / (float)TKN);
      float ce = (float)base[e] * (1.0f / (float)TKN);
      s += me * ce;
    }
    *out_laux = (float)NEXP * s;
  }
}

// ---------------- dispatch: scatter tokens as bf16, zero dropped out rows ----------------
__global__ __launch_bounds__(256) void k_dispatch(const float* __restrict__ x,
                                                  const int* __restrict__ top1,
                                                  const int* __restrict__ rankk,
                                                  int* __restrict__ slot_token,
                                                  unsigned short* __restrict__ Xb,
                                                  float* __restrict__ out) {
  const int t = blockIdx.x;
  const int tid = threadIdx.x;
  const int r = rankk[t];
  if (r < 0) {
    float4 z = {0.f, 0.f, 0.f, 0.f};
    *(float4*)(out + (size_t)t * DMODEL + tid * 4) = z;
    return;
  }
  const int e = top1[t];
  const int slot = e * CAPC + r;
  if (tid == 0) slot_token[slot] = t;
  float4 v = *(const float4*)(x + (size_t)t * DMODEL + tid * 4);
  ushort4 h;
  h.x = f2bf(v.x); h.y = f2bf(v.y); h.z = f2bf(v.z); h.w = f2bf(v.w);
  *(ushort4*)(Xb + (size_t)slot * DMODEL + tid * 4) = h;
}

// ---------------- weight transpose + fp32->bf16: W[e][K][N] -> WT[e][Nt][Kt] ----------------
__global__ __launch_bounds__(256) void k_wtrans(const float* __restrict__ W,
                                                unsigned short* __restrict__ WT,
                                                int K, int N, int k_off, int Kt,
                                                int n_off, int Nt) {
  __shared__ float ls[32][33];
  const int e = blockIdx.z, kt = blockIdx.y, nt = blockIdx.x;
  const int t = threadIdx.x;
  {
    const int kl = t >> 3, nl0 = (t & 7) * 4;
    const float* src = W + (size_t)e * K * N + (size_t)(k_off + kt * 32 + kl) * N + n_off + nt * 32 + nl0;
    float4 v = *(const float4*)src;
    ls[kl][nl0 + 0] = v.x; ls[kl][nl0 + 1] = v.y;
    ls[kl][nl0 + 2] = v.z; ls[kl][nl0 + 3] = v.w;
  }
  __syncthreads();
  {
    const int nl = t >> 3, kl0 = (t & 7) * 4;
    ushort4 o;
    o.x = f2bf(ls[kl0 + 0][nl]); o.y = f2bf(ls[kl0 + 1][nl]);
    o.z = f2bf(ls[kl0 + 2][nl]); o.w = f2bf(ls[kl0 + 3][nl]);
    *(ushort4*)(WT + (size_t)e * Nt * Kt + (size_t)(nt * 32 + nl) * Kt + kt * 32 + kl0) = o;
  }
}

// ---------------- MFMA GEMM: 128x128 tile, dbuf LDS, counted vmcnt, XOR swizzle --------
// MODE 0: H = f2bf(gelu(acc + b1))   MODE 1: out[t] = p*acc   MODE 2: out[t] += p*(acc + b2)
template <int MODE>
__global__ __launch_bounds__(256) void k_gemm(
    const unsigned short* __restrict__ A, int lda,
    const unsigned short* __restrict__ Bm, int ldb,
    int nK,
    const float* __restrict__ bias, int bias_off, int bias_ld,
    unsigned short* __restrict__ Hout, int ldh,
    const int* __restrict__ slot_token,
    const float* __restrict__ p1,
    float* __restrict__ out) {
  __shared__ __align__(16) unsigned short As[2][128 * 64];
  __shared__ __align__(16) unsigned short Bs[2][128 * 64];
  const int e = blockIdx.z, mt = blockIdx.y, nt = blockIdx.x;
  const int tid = threadIdx.x;
  const int w = tid >> 6, lane = tid & 63;
  const int wr = w >> 1, wc = w & 1;
  const int N = gridDim.x * 128;

  const unsigned short* Abase = A + (size_t)(e * CAPC + mt * 128) * lda;
  const unsigned short* Bbase = Bm + (size_t)e * N * ldb + (size_t)(nt * 128) * ldb;

  // Staging geometry. LDS dest is linear (wave-uniform base + lane*16B);
  // source k-slot pre-swizzled so LDS[r][s] holds global (r, s ^ (r&7)).
  const int srow_base = w * 32 + (lane >> 3);       // + j*8
  const int sslot = (lane & 7) ^ (lane >> 3);       // pre-swizzled source 16B-slot

  f32x4 acc[4][4];
#pragma unroll
  for (int m = 0; m < 4; ++m)
#pragma unroll
    for (int n = 0; n < 4; ++n) acc[m][n] = (f32x4){0.f, 0.f, 0.f, 0.f};

  // Fragment read geometry (swizzled): element (row, kk + hi*8) lives at
  // row*64 + (((kk>>3)+hi) ^ (row&7))*8.  row&7 == lane&7 for all frags.
  const int arow = wr * 64 + (lane & 15);  // + m*16
  const int brow = wc * 64 + (lane & 15);  // + n*16
  const int hi = lane >> 4;
  const int rm = lane & 7;

#define STAGE_TILE(buf, t)                                                              \
  do {                                                                                  \
    const size_t k0s = (size_t)(t) * 64 + (size_t)sslot * 8;                            \
    _Pragma("unroll") for (int j = 0; j < 4; ++j)                                       \
        gload_lds16(Abase + (size_t)(srow_base + j * 8) * lda + k0s,                    \
                    &As[buf][(w * 32 + j * 8) * 64]);                                   \
    _Pragma("unroll") for (int j = 0; j < 4; ++j)                                       \
        gload_lds16(Bbase + (size_t)(srow_base + j * 8) * ldb + k0s,                    \
                    &Bs[buf][(w * 32 + j * 8) * 64]);                                   \
  } while (0)

  STAGE_TILE(0, 0);
  for (int t = 0; t < nK; ++t) {
    const int cur = t & 1;
    if (t + 1 < nK) {
      STAGE_TILE(cur ^ 1, t + 1);
      asm volatile("s_waitcnt vmcnt(8)" ::: "memory");   // tile t landed; t+1 in flight
    } else {
      asm volatile("s_waitcnt vmcnt(0)" ::: "memory");
    }
    __builtin_amdgcn_sched_barrier(0);
    __builtin_amdgcn_s_barrier();

#pragma unroll
    for (int kk = 0; kk < 64; kk += 32) {
      const int sb = (kk >> 3) + hi;
      short8 av[4], bv[4];
#pragma unroll
      for (int m = 0; m < 4; ++m)
        av[m] = *(const short8*)&As[cur][(arow + m * 16) * 64 + ((sb ^ rm) << 3)];
#pragma unroll
      for (int n = 0; n < 4; ++n)
        bv[n] = *(const short8*)&Bs[cur][(brow + n * 16) * 64 + ((sb ^ rm) << 3)];
#pragma unroll
      for (int m = 0; m < 4; ++m)
#pragma unroll
        for (int n = 0; n < 4; ++n)
          acc[m][n] = __builtin_amdgcn_mfma_f32_16x16x32_bf16(av[m], bv[n], acc[m][n], 0, 0, 0);
    }

    asm volatile("s_waitcnt lgkmcnt(0)" ::: "memory");   // our ds_reads done
    __builtin_amdgcn_sched_barrier(0);
    __builtin_amdgcn_s_barrier();                        // buf[cur] now safe to overwrite
  }
#undef STAGE_TILE

  const int colf = lane & 15;
  const int rsub = (lane >> 4) * 4;
#pragma unroll
  for (int m = 0; m < 4; ++m) {
#pragma unroll
    for (int i = 0; i < 4; ++i) {
      const int slot_l = mt * 128 + wr * 64 + m * 16 + rsub + i;
      if (MODE == 0) {
        const size_t hrow = ((size_t)(e * CAPC) + slot_l) * ldh;
#pragma unroll
        for (int n = 0; n < 4; ++n) {
          const int col = nt * 128 + wc * 64 + n * 16 + colf;
          float v = acc[m][n][i] + bias[e * bias_ld + bias_off + col];
          Hout[hrow + col] = f2bf(gelu_tanh(v));
        }
      } else {
        const int slotg = e * CAPC + slot_l;
        const int tkn = slot_token[slotg];
        if (tkn >= 0) {
          const float p = p1[tkn];
#pragma unroll
          for (int n = 0; n < 4; ++n) {
            const int col = nt * 128 + wc * 64 + n * 16 + colf;
            float v = acc[m][n][i];
            if (MODE == 2) v += bias[e * bias_ld + col];
            float o = p * v;
            float* dst = out + (size_t)tkn * DMODEL + col;
            if (MODE == 2) *dst = *dst + o;
            else *dst = o;
          }
        }
      }
    }
  }
}

extern "C" void kernel_launch(void* const* d_in, const int* in_sizes, int n_in,
                              void* d_out, int out_size, void* d_ws, size_t ws_size,
                              hipStream_t stream) {
  const float* x  = (const float*)d_in[0];
  const float* gw = (const float*)d_in[1];
  const float* w1 = (const float*)d_in[2];
  const float* b1 = (const float*)d_in[3];
  const float* w2 = (const float*)d_in[4];
  const float* b2 = (const float*)d_in[5];
  float* out = (float*)d_out;

  char* ws = (char*)d_ws;
  float* me_sum     = (float*)(ws + 0);
  int*   top1       = (int*)(ws + 1024);
  float* p1         = (float*)(ws + 33792);
  int*   rankk      = (int*)(ws + 66560);
  int*   slot_token = (int*)(ws + 99328);
  unsigned short* Xb = (unsigned short*)(ws + 140288);               // 20.97 MB
  unsigned short* H  = (unsigned short*)(ws + 21111808);             // 41.94 MB
  unsigned short* WB = (unsigned short*)(ws + 63054848);             // 33.55 MB
  // total ~96.6 MB

  k_init<<<40, 256, 0, stream>>>(slot_token, me_sum);
  k_gate<<<TKN / 4, 256, 0, stream>>>(x, gw, top1, p1, me_sum);
  k_scan<<<1, 1024, 0, stream>>>(top1, me_sum, rankk, out + (size_t)TKN * DMODEL);
  k_dispatch<<<TKN, 256, 0, stream>>>(x, top1, rankk, slot_token, Xb, out);

  // ---- half 0 (f in [0,2048)) ----
  k_wtrans<<<dim3(64, 32, NEXP), 256, 0, stream>>>(w1, WB, DMODEL, DFFN, 0, DMODEL, 0, 2048);
  k_gemm<0><<<dim3(16, 10, NEXP), 256, 0, stream>>>(Xb, DMODEL, WB, DMODEL, DMODEL / 64,
                                                    b1, 0, DFFN, H, 2048,
                                                    nullptr, nullptr, nullptr);
  k_wtrans<<<dim3(32, 64, NEXP), 256, 0, stream>>>(w2, WB, DFFN, DMODEL, 0, 2048, 0, DMODEL);
  k_gemm<1><<<dim3(8, 10, NEXP), 256, 0, stream>>>(H, 2048, WB, 2048, 2048 / 64,
                                                   b2, 0, DMODEL, nullptr, 0,
                                                   slot_token, p1, out);

  // ---- half 1 (f in [2048,4096)) ----
  k_wtrans<<<dim3(64, 32, NEXP), 256, 0, stream>>>(w1, WB, DMODEL, DFFN, 0, DMODEL, 2048, 2048);
  k_gemm<0><<<dim3(16, 10, NEXP), 256, 0, stream>>>(Xb, DMODEL, WB, DMODEL, DMODEL / 64,
                                                    b1, 2048, DFFN, H, 2048,
                                                    nullptr, nullptr, nullptr);
  k_wtrans<<<dim3(32, 64, NEXP), 256, 0, stream>>>(w2, WB, DFFN, DMODEL, 2048, 2048, 0, DMODEL);
  k_gemm<2><<<dim3(8, 10, NEXP), 256, 0, stream>>>(H, 2048, WB, 2048, 2048 / 64,
                                                   b2, 0, DMODEL, nullptr, 0,
                                                   slot_token, p1, out);
}